// Round 1
// baseline (427.520 us; speedup 1.0000x reference)
//
#include <hip/hip_runtime.h>

// o_x[r,c] = l_xx*X[r,c] + g_xx*sumX[r] + g_yx*sumY[r]
// o_y[r,c] = l_yy*Y[r,c] + g_yy*sumY[r] + g_xy*sumX[r]
// R=8192 rows, N=4096 cols.
//
// 256-thread block per row: 4 float4 of X + 4 float4 of Y per thread.
//   - 8 independent 16B loads in flight per thread (4x the MLP of the
//     1024-thread version) -> latency hiding by ILP, not just occupancy.
//   - __syncthreads spans only 4 waves; up to 8 blocks/CU co-resident,
//     so a barriered block's stall is hidden by 7 others.
//   - reduction cost (12 shfl + LDS combine) amortized over 32 elems/thread.
// ~55 VGPR -> fits the 64-reg budget of __launch_bounds__(256,8): 32 waves/CU.

constexpr int N_COLS = 4096;
constexpr int THREADS = 256;          // 4 waves; 4 float4 per matrix per thread

typedef float v4f __attribute__((ext_vector_type(4)));

static __device__ __forceinline__ v4f affine4(v4f v, float l, float b) {
    v4f r;
    r.x = fmaf(l, v.x, b);
    r.y = fmaf(l, v.y, b);
    r.z = fmaf(l, v.z, b);
    r.w = fmaf(l, v.w, b);
    return r;
}

__global__ __launch_bounds__(THREADS, 8) void pequinn_rowaffine(
    const float* __restrict__ X, const float* __restrict__ Y,
    const float* __restrict__ p_lxx, const float* __restrict__ p_lyy,
    const float* __restrict__ p_gxx, const float* __restrict__ p_gxy,
    const float* __restrict__ p_gyx, const float* __restrict__ p_gyy,
    float* __restrict__ o_x, float* __restrict__ o_y)
{
    const int row = blockIdx.x;
    const int tid = threadIdx.x;            // 0..255
    const size_t base = (size_t)row * N_COLS;

    const v4f* Xr = (const v4f*)(X + base) + tid;
    const v4f* Yr = (const v4f*)(Y + base) + tid;

    // 8 independent streaming loads issued back-to-back.
    v4f x0 = __builtin_nontemporal_load(Xr);
    v4f x1 = __builtin_nontemporal_load(Xr + 256);
    v4f x2 = __builtin_nontemporal_load(Xr + 512);
    v4f x3 = __builtin_nontemporal_load(Xr + 768);
    v4f y0 = __builtin_nontemporal_load(Yr);
    v4f y1 = __builtin_nontemporal_load(Yr + 256);
    v4f y2 = __builtin_nontemporal_load(Yr + 512);
    v4f y3 = __builtin_nontemporal_load(Yr + 768);

    // Uniform scalar params -> s_load; latency hidden under the loads above.
    const float lxx = p_lxx[0], lyy = p_lyy[0];
    const float gxx = p_gxx[0], gxy = p_gxy[0];
    const float gyx = p_gyx[0], gyy = p_gyy[0];

    // Per-thread partial sums (pairwise, vectorized).
    v4f xs = (x0 + x1) + (x2 + x3);
    v4f ys = (y0 + y1) + (y2 + y3);
    float sx = (xs.x + xs.y) + (xs.z + xs.w);
    float sy = (ys.x + ys.y) + (ys.z + ys.w);

    // Wave-64 butterfly reduce.
#pragma unroll
    for (int off = 32; off > 0; off >>= 1) {
        sx += __shfl_down(sx, off, 64);
        sy += __shfl_down(sy, off, 64);
    }

    // Cross-wave combine via LDS (only 4 waves / block).
    __shared__ float ssx[4], ssy[4];
    const int wave = tid >> 6;
    if ((tid & 63) == 0) { ssx[wave] = sx; ssy[wave] = sy; }
    __syncthreads();

    const float SX = (ssx[0] + ssx[1]) + (ssx[2] + ssx[3]);   // broadcast reads
    const float SY = (ssy[0] + ssy[1]) + (ssy[2] + ssy[3]);

    const float bx = fmaf(gxx, SX, gyx * SY);   // row-constant term for o_x
    const float by = fmaf(gyy, SY, gxy * SX);   // row-constant term for o_y

    v4f* Ox = (v4f*)(o_x + base) + tid;
    v4f* Oy = (v4f*)(o_y + base) + tid;

    __builtin_nontemporal_store(affine4(x0, lxx, bx), Ox);
    __builtin_nontemporal_store(affine4(x1, lxx, bx), Ox + 256);
    __builtin_nontemporal_store(affine4(x2, lxx, bx), Ox + 512);
    __builtin_nontemporal_store(affine4(x3, lxx, bx), Ox + 768);
    __builtin_nontemporal_store(affine4(y0, lyy, by), Oy);
    __builtin_nontemporal_store(affine4(y1, lyy, by), Oy + 256);
    __builtin_nontemporal_store(affine4(y2, lyy, by), Oy + 512);
    __builtin_nontemporal_store(affine4(y3, lyy, by), Oy + 768);
}

extern "C" void kernel_launch(void* const* d_in, const int* in_sizes, int n_in,
                              void* d_out, int out_size, void* d_ws, size_t ws_size,
                              hipStream_t stream) {
    const float* X    = (const float*)d_in[0];
    const float* Y    = (const float*)d_in[1];
    const float* lxx  = (const float*)d_in[2];
    const float* lyy  = (const float*)d_in[3];
    const float* gxx  = (const float*)d_in[4];
    const float* gxy  = (const float*)d_in[5];
    const float* gyx  = (const float*)d_in[6];
    const float* gyy  = (const float*)d_in[7];

    const int R = in_sizes[0] / N_COLS;     // 8192
    float* o_x = (float*)d_out;                       // first output, R*N floats
    float* o_y = (float*)d_out + (size_t)R * N_COLS;  // second output

    pequinn_rowaffine<<<R, THREADS, 0, stream>>>(X, Y, lxx, lyy, gxx, gxy, gyx, gyy,
                                                 o_x, o_y);
}